// Round 4
// baseline (716.080 us; speedup 1.0000x reference)
//
#include <hip/hip_runtime.h>
#include <math.h>

#define NEG_SLOPE 0.05f

__device__ __forceinline__ float leaky(float x){ return x >= 0.f ? x : NEG_SLOPE * x; }

// bf16 helpers (RNE pack, truncated-float unpack)
__device__ __forceinline__ unsigned short f2bf(float f){
    unsigned u = __float_as_uint(f);
    unsigned r = u + 0x7FFFu + ((u >> 16) & 1u);
    return (unsigned short)(r >> 16);
}
__device__ __forceinline__ float bf2f(unsigned short us){
    return __uint_as_float((unsigned)us << 16);
}

// wave-aligned slice boundaries: slice g covers nodes [slice_lo(g), slice_lo(g+1))
__device__ __forceinline__ int slice_lo(int g, int N){
    long long v = ((((long long)g * N) >> 3) + 63LL) & ~63LL;
    return (int)(v > (long long)N ? (long long)N : v);
}
__device__ __forceinline__ int slice_of_wave(int w0, int N){
    int g = 0;
    #pragma unroll
    for (int q = 1; q < 8; q++) if (w0 >= slice_lo(q, N)) g = q;
    return g;
}

// ---------------- K0: zero degree arrays + slice counters; precompute vv = We^T @ a_edge[64:] ----------------
__global__ __launch_bounds__(256) void k_init(int* deg_n, int* deg_o, int* sctr,
        float* __restrict__ vv, const float* __restrict__ We, const float* __restrict__ a_edge, int N){
    int t = blockIdx.x * blockDim.x + threadIdx.x;
    if (t < 16) sctr[t] = 0;
    if (t < 64){
        float s = 0.f;
        for (int d = 0; d < 64; d++) s = fmaf(We[d * 64 + t], a_edge[64 + d], s);
        vv[t] = s;
    }
    int stride = gridDim.x * blockDim.x;
    for (int i = t; i < N; i += stride){ deg_n[i] = 0; deg_o[i] = 0; }
}

// ---------------- GEMM h = x @ Wn^T  (+ bf16 copy + fused hi/hj/he epilogue) ----------------
__global__ __launch_bounds__(256) void k_gemm_h(const float* __restrict__ A, const float* __restrict__ B,
        const float* __restrict__ a_node, const float* __restrict__ a_edge,
        float* __restrict__ C, unsigned short* __restrict__ Cb,
        float* __restrict__ hi, float* __restrict__ hj, float* __restrict__ he, int M){
    const int K = 128;
    __shared__ float As[K][68];
    __shared__ float Bs[K][68];
    const int m0 = blockIdx.x * 64;
    const int t = threadIdx.x;
    for (int i = t; i < 16 * K; i += 256){
        int d = i & 63, kq = i >> 6;
        float4 b = *(const float4*)&B[(size_t)d * K + kq * 4];
        Bs[kq*4+0][d] = b.x; Bs[kq*4+1][d] = b.y; Bs[kq*4+2][d] = b.z; Bs[kq*4+3][d] = b.w;
    }
    for (int i = t; i < 16 * K; i += 256){
        int r = i & 63, kq = i >> 6;
        int m = m0 + r;
        float4 a = make_float4(0.f, 0.f, 0.f, 0.f);
        if (m < M) a = *(const float4*)&A[(size_t)m * K + kq * 4];
        As[kq*4+0][r] = a.x; As[kq*4+1][r] = a.y; As[kq*4+2][r] = a.z; As[kq*4+3][r] = a.w;
    }
    __syncthreads();
    const int tx = t & 15, ty = t >> 4;
    float acc[4][4] = {};
    #pragma unroll 4
    for (int k = 0; k < K; k++){
        float4 a4 = *(const float4*)&As[k][ty * 4];
        float4 b4 = *(const float4*)&Bs[k][tx * 4];
        float av[4] = {a4.x, a4.y, a4.z, a4.w};
        float bv[4] = {b4.x, b4.y, b4.z, b4.w};
        #pragma unroll
        for (int r = 0; r < 4; r++)
            #pragma unroll
            for (int c = 0; c < 4; c++)
                acc[r][c] = fmaf(av[r], bv[c], acc[r][c]);
    }
    #pragma unroll
    for (int r = 0; r < 4; r++){
        int m = m0 + ty * 4 + r;
        if (m < M){
            float4 o = make_float4(acc[r][0], acc[r][1], acc[r][2], acc[r][3]);
            *(float4*)&C[(size_t)m * 64 + tx * 4] = o;
            uint2 u;
            u.x = (unsigned)f2bf(o.x) | ((unsigned)f2bf(o.y) << 16);
            u.y = (unsigned)f2bf(o.z) | ((unsigned)f2bf(o.w) << 16);
            *(uint2*)&Cb[(size_t)m * 64 + tx * 4] = u;
        }
    }
    // fused per-row scalars: hi = h.a_node[:64], hj = h.a_node[64:], he = h.a_edge[:64]
    float4 an1 = *(const float4*)&a_node[tx * 4];
    float4 an2 = *(const float4*)&a_node[64 + tx * 4];
    float4 ae1 = *(const float4*)&a_edge[tx * 4];
    float p1[4], p2[4], p3[4];
    #pragma unroll
    for (int r = 0; r < 4; r++){
        p1[r] = acc[r][0]*an1.x + acc[r][1]*an1.y + acc[r][2]*an1.z + acc[r][3]*an1.w;
        p2[r] = acc[r][0]*an2.x + acc[r][1]*an2.y + acc[r][2]*an2.z + acc[r][3]*an2.w;
        p3[r] = acc[r][0]*ae1.x + acc[r][1]*ae1.y + acc[r][2]*ae1.z + acc[r][3]*ae1.w;
    }
    #pragma unroll
    for (int m = 1; m < 16; m <<= 1){
        #pragma unroll
        for (int r = 0; r < 4; r++){
            p1[r] += __shfl_xor(p1[r], m);
            p2[r] += __shfl_xor(p2[r], m);
            p3[r] += __shfl_xor(p3[r], m);
        }
    }
    if (tx == 0){
        #pragma unroll
        for (int r = 0; r < 4; r++){
            int m = m0 + ty * 4 + r;
            if (m < M){ hi[m] = p1[r]; hj[m] = p2[r]; he[m] = p3[r]; }
        }
    }
}

// ---------------- degree count (idx only, XCD-partitioned) ----------------
__global__ __launch_bounds__(256) void k_count(const int* __restrict__ idx,
        int* __restrict__ deg_n, int* __restrict__ deg_o, int E, int N){
    int g = blockIdx.x & 7;
    int lo = slice_lo(g, N), hi = slice_lo(g + 1, N);
    int nblk = gridDim.x >> 3;
    int start = ((blockIdx.x >> 3) * 256) + threadIdx.x;
    int stride = nblk * 256;
    for (int k = start; k < E; k += stride){
        int i0 = idx[k], i1 = idx[E + k];
        if (i0 >= lo && i0 < hi) atomicAdd(&deg_n[i0], 1);
        if (i1 >= lo && i1 < hi) atomicAdd(&deg_o[i1], 1);
    }
}

// ---------------- offset pass A: per-slice totals (incident degree only) ----------------
__global__ __launch_bounds__(256) void k_off_a(const int* __restrict__ deg_n, const int* __restrict__ deg_o,
        int* __restrict__ sctr, int N){
    int i = blockIdx.x * 256 + threadIdx.x;
    int lane = threadIdx.x & 63;
    int de = 0;
    if (i < N) de = deg_n[i] + deg_o[i];
    int pe = de;
    #pragma unroll
    for (int d = 1; d < 64; d <<= 1) pe += __shfl_xor(pe, d);
    if (lane == 0 && i < N){
        int g = slice_of_wave(i, N);
        atomicAdd(&sctr[g], pe);
    }
}

// ---------------- offset pass B: slice-grouped assignment ----------------
__global__ __launch_bounds__(256) void k_off_b(const int* __restrict__ deg_n, const int* __restrict__ deg_o,
        int* __restrict__ deg_e, int* __restrict__ off_e, int* __restrict__ cur_e,
        int* __restrict__ sctr, int N){
    int i = blockIdx.x * 256 + threadIdx.x;
    int lane = threadIdx.x & 63;
    int de = 0;
    if (i < N) de = deg_n[i] + deg_o[i];
    int pe = de;   // inclusive wave scan
    #pragma unroll
    for (int d = 1; d < 64; d <<= 1){
        int oe = __shfl_up(pe, d);
        if (lane >= d) pe += oe;
    }
    int w0 = i - lane;
    int base_e = 0;
    if (lane == 63 && w0 < N){
        int g = slice_of_wave(w0, N);
        int be = 0;
        for (int q = 0; q < g; q++) be += sctr[q];
        base_e = be + atomicAdd(&sctr[8 + g], pe);
    }
    base_e = __shfl(base_e, 63);
    if (i < N){
        int oe = base_e + pe - de;
        off_e[i] = oe; cur_e[i] = oe;
        deg_e[i] = de;
    }
}

// ---------------- position assignment (XCD-partitioned atomic bump; sequential pos writes) ----------------
__global__ __launch_bounds__(256) void k_fillpos(const int* __restrict__ idx,
        int* __restrict__ cur_e, int* __restrict__ pos0, int* __restrict__ pos1, int E, int N){
    int g = blockIdx.x & 7;
    int lo = slice_lo(g, N), hi = slice_lo(g + 1, N);
    int nblk = gridDim.x >> 3;
    int start = ((blockIdx.x >> 3) * 256) + threadIdx.x;
    int stride = nblk * 256;
    for (int k = start; k < E; k += stride){
        int i0 = idx[k], i1 = idx[E + k];
        if (i0 >= lo && i0 < hi) pos0[k] = atomicAdd(&cur_e[i0], 1);
        if (i1 >= lo && i1 < hi) pos1[k] = atomicAdd(&cur_e[i1], 1);
    }
}

// ---------------- ea stream: ge in-pass, scatter bf16 rows + records to final adjacency slots ----------------
// record: {x = j | (target?0x80000000:0), y = hj[j] bits (target side only), z = ge bits, w = pad}
__global__ __launch_bounds__(256) void k_ge3(const float* __restrict__ ea, const int* __restrict__ idx,
        const int* __restrict__ pos0, const int* __restrict__ pos1,
        const float* __restrict__ vv, const float* __restrict__ hj,
        unsigned short* __restrict__ eseq, int4* __restrict__ rec, int E){
    int l = threadIdx.x & 63;
    int gw = (blockIdx.x * 256 + threadIdx.x) >> 6;
    int nw = (gridDim.x * 256) >> 6;
    int seg = l & 15, rl = l >> 4;
    int leader = rl << 4;
    float4 v4 = *(const float4*)&vv[seg * 4];
    for (int r0 = gw * 4; r0 < E; r0 += nw * 4){
        int row = r0 + rl;
        if (row < E){
            float4 a = *(const float4*)&ea[(size_t)row * 64 + seg * 4];
            float s = a.x*v4.x + a.y*v4.y + a.z*v4.z + a.w*v4.w;
            #pragma unroll
            for (int m = 1; m < 16; m <<= 1) s += __shfl_xor(s, m);
            uint2 u;
            u.x = (unsigned)f2bf(a.x) | ((unsigned)f2bf(a.y) << 16);
            u.y = (unsigned)f2bf(a.z) | ((unsigned)f2bf(a.w) << 16);
            int p0 = 0, p1 = 0;
            if (seg == 0){ p0 = pos0[row]; p1 = pos1[row]; }
            p0 = __shfl(p0, leader);
            p1 = __shfl(p1, leader);
            *(uint2*)&eseq[(size_t)p0 * 64 + seg * 4] = u;
            *(uint2*)&eseq[(size_t)p1 * 64 + seg * 4] = u;
            if (seg == 0){
                int i0 = idx[row], i1 = idx[E + row];
                rec[p0] = make_int4((int)((unsigned)i1 | 0x80000000u), __float_as_int(hj[i1]), __float_as_int(s), 0);
                rec[p1] = make_int4(i0, 0, __float_as_int(s), 0);
            }
        }
    }
}

// ---------------- unified output kernel: one sequential pass over incidence list per node ----------------
__global__ __launch_bounds__(256) void k_out(const float* __restrict__ h,
        const unsigned short* __restrict__ hb, const unsigned short* __restrict__ eseq,
        const int4* __restrict__ rec,
        const float* __restrict__ hi, const float* __restrict__ hj, const float* __restrict__ he,
        const float* __restrict__ We,
        const int* __restrict__ off_e, const int* __restrict__ deg_e, const int* __restrict__ deg_n,
        float* __restrict__ out, int N){
    __shared__ float WeT[64][65];
    __shared__ float valS[4][64];
    const int lane = threadIdx.x & 63;
    const int w = threadIdx.x >> 6;
    const int rl = lane >> 4, seg = lane & 15;

    for (int t2 = threadIdx.x; t2 < 1024; t2 += 256){
        int d = t2 >> 4, c0 = (t2 & 15) * 4;
        float4 v = *(const float4*)&We[d * 64 + c0];
        WeT[c0+0][d] = v.x; WeT[c0+1][d] = v.y; WeT[c0+2][d] = v.z; WeT[c0+3][d] = v.w;
    }

    int i = (blockIdx.x * 256 + (int)threadIdx.x) >> 6;
    const bool iok = (i < N);
    float an0=0.f, an1=0.f, an2=0.f, an3=0.f, sn=0.f;
    float ae0=0.f, ae1=0.f, ae2=0.f, ae3=0.f, se=0.f;
    float hi_i = 0.f, he_i = 0.f;
    int cnt = 0, cntn = 0;
    if (iok){
        hi_i = hi[i]; he_i = he[i];
        cnt = deg_e[i]; cntn = deg_n[i];
        int p = off_e[i], e = p + cnt;
        for (; p + 4 <= e; p += 4){
            int4 r = rec[p + rl];
            uint2 ue = *(const uint2*)&eseq[(size_t)(p + rl) * 64 + seg * 4];
            float we_ = __expf(leaky(he_i + __int_as_float(r.z)));
            ae0 = fmaf(we_, bf2f((unsigned short)ue.x), ae0);
            ae1 = fmaf(we_, bf2f((unsigned short)(ue.x >> 16)), ae1);
            ae2 = fmaf(we_, bf2f((unsigned short)ue.y), ae2);
            ae3 = fmaf(we_, bf2f((unsigned short)(ue.y >> 16)), ae3);
            se += we_;
            if (r.x < 0){
                int j = r.x & 0x7fffffff;
                float wn_ = __expf(leaky(hi_i + __int_as_float(r.y)));
                uint2 un = *(const uint2*)&hb[(size_t)j * 64 + seg * 4];
                an0 = fmaf(wn_, bf2f((unsigned short)un.x), an0);
                an1 = fmaf(wn_, bf2f((unsigned short)(un.x >> 16)), an1);
                an2 = fmaf(wn_, bf2f((unsigned short)un.y), an2);
                an3 = fmaf(wn_, bf2f((unsigned short)(un.y >> 16)), an3);
                sn += wn_;
            }
        }
        int rem = e - p;
        if (rl < rem){
            int4 r = rec[p + rl];
            uint2 ue = *(const uint2*)&eseq[(size_t)(p + rl) * 64 + seg * 4];
            float we_ = __expf(leaky(he_i + __int_as_float(r.z)));
            ae0 = fmaf(we_, bf2f((unsigned short)ue.x), ae0);
            ae1 = fmaf(we_, bf2f((unsigned short)(ue.x >> 16)), ae1);
            ae2 = fmaf(we_, bf2f((unsigned short)ue.y), ae2);
            ae3 = fmaf(we_, bf2f((unsigned short)(ue.y >> 16)), ae3);
            se += we_;
            if (r.x < 0){
                int j = r.x & 0x7fffffff;
                float wn_ = __expf(leaky(hi_i + __int_as_float(r.y)));
                uint2 un = *(const uint2*)&hb[(size_t)j * 64 + seg * 4];
                an0 = fmaf(wn_, bf2f((unsigned short)un.x), an0);
                an1 = fmaf(wn_, bf2f((unsigned short)(un.x >> 16)), an1);
                an2 = fmaf(wn_, bf2f((unsigned short)un.y), an2);
                an3 = fmaf(wn_, bf2f((unsigned short)(un.y >> 16)), an3);
                sn += wn_;
            }
        }
    }
    // reduce across the 4 rl groups
    an0 += __shfl_xor(an0, 16); an0 += __shfl_xor(an0, 32);
    an1 += __shfl_xor(an1, 16); an1 += __shfl_xor(an1, 32);
    an2 += __shfl_xor(an2, 16); an2 += __shfl_xor(an2, 32);
    an3 += __shfl_xor(an3, 16); an3 += __shfl_xor(an3, 32);
    sn  += __shfl_xor(sn, 16);  sn  += __shfl_xor(sn, 32);
    ae0 += __shfl_xor(ae0, 16); ae0 += __shfl_xor(ae0, 32);
    ae1 += __shfl_xor(ae1, 16); ae1 += __shfl_xor(ae1, 32);
    ae2 += __shfl_xor(ae2, 16); ae2 += __shfl_xor(ae2, 32);
    ae3 += __shfl_xor(ae3, 16); ae3 += __shfl_xor(ae3, 32);
    se  += __shfl_xor(se, 16);  se  += __shfl_xor(se, 32);

    // node epilogue (self loop + mean + leaky) -> out[:, :64]
    if (iok && rl == 0){
        float4 h4 = *(const float4*)&h[(size_t)i * 64 + seg * 4];
        float wself = __expf(leaky(hi_i + hj[i]));
        float s = sn + wself;
        float inv = 1.f / (s * (float)(cntn + 1));
        float4 o;
        o.x = leaky(fmaf(wself, h4.x, an0) * inv);
        o.y = leaky(fmaf(wself, h4.y, an1) * inv);
        o.z = leaky(fmaf(wself, h4.z, an2) * inv);
        o.w = leaky(fmaf(wself, h4.w, an3) * inv);
        *(float4*)&out[(size_t)i * 128 + seg * 4] = o;
    }
    // edge epilogue: mean -> valS, then fused @ We^T -> out[:, 64:]
    float v0 = 0.f, v1 = 0.f, v2 = 0.f, v3 = 0.f;
    if (iok && cnt > 0){
        float inv = 1.f / (se * (float)cnt);
        v0 = ae0 * inv; v1 = ae1 * inv; v2 = ae2 * inv; v3 = ae3 * inv;
    }
    __syncthreads();                 // WeT ready
    if (rl == 0) *(float4*)&valS[w][seg * 4] = make_float4(v0, v1, v2, v3);
    __syncthreads();                 // valS visible
    if (iok){
        float acc2 = 0.f;
        #pragma unroll
        for (int c4 = 0; c4 < 16; c4++){
            float4 vb = *(const float4*)&valS[w][c4 * 4];
            acc2 = fmaf(vb.x, WeT[c4*4+0][lane], acc2);
            acc2 = fmaf(vb.y, WeT[c4*4+1][lane], acc2);
            acc2 = fmaf(vb.z, WeT[c4*4+2][lane], acc2);
            acc2 = fmaf(vb.w, WeT[c4*4+3][lane], acc2);
        }
        out[(size_t)i * 128 + 64 + lane] = leaky(acc2);
    }
}

extern "C" void kernel_launch(void* const* d_in, const int* in_sizes, int n_in,
                              void* d_out, int out_size, void* d_ws, size_t ws_size,
                              hipStream_t stream){
    const float* x      = (const float*)d_in[0];
    const float* ea     = (const float*)d_in[1];
    const int*   idx    = (const int*)  d_in[2];
    const float* Wn     = (const float*)d_in[3];
    const float* We     = (const float*)d_in[4];
    const float* a_node = (const float*)d_in[5];
    const float* a_edge = (const float*)d_in[6];
    float* out = (float*)d_out;

    const int N = in_sizes[0] / 128;   // 50000
    const int E = in_sizes[1] / 64;    // 800000

    float* p = (float*)d_ws;
    float* h      = p; p += (size_t)N * 64;
    float* hi     = p; p += N;
    float* hj     = p; p += N;
    float* he     = p; p += N;
    float* vv     = p; p += 64;
    unsigned short* hb = (unsigned short*)p; p += (size_t)N * 32;    // bf16 h
    int* deg_n = (int*)p; p += N;
    int* deg_o = (int*)p; p += N;
    int* deg_e = (int*)p; p += N;
    int* off_e = (int*)p; p += N;
    int* cur_e = (int*)p; p += N;
    int* pos0  = (int*)p; p += E;
    int* pos1  = (int*)p; p += E;
    int* sctr  = (int*)p; p += 16;
    p = (float*)(((size_t)p + 15) & ~(size_t)15);                    // 16B align
    int4* rec = (int4*)p; p += (size_t)2 * E * 4;                    // 2E x 16B
    unsigned short* eseq = (unsigned short*)p;                       // 2E x 128B bf16 rows

    k_init<<<256, 256, 0, stream>>>(deg_n, deg_o, sctr, vv, We, a_edge, N);
    k_gemm_h<<<(N + 63) / 64, 256, 0, stream>>>(x, Wn, a_node, a_edge, h, hb, hi, hj, he, N);
    k_count<<<1024, 256, 0, stream>>>(idx, deg_n, deg_o, E, N);
    k_off_a<<<(N + 255) / 256, 256, 0, stream>>>(deg_n, deg_o, sctr, N);
    k_off_b<<<(N + 255) / 256, 256, 0, stream>>>(deg_n, deg_o, deg_e, off_e, cur_e, sctr, N);
    k_fillpos<<<1024, 256, 0, stream>>>(idx, cur_e, pos0, pos1, E, N);
    k_ge3<<<2048, 256, 0, stream>>>(ea, idx, pos0, pos1, vv, hj, eseq, rec, E);
    k_out<<<(N + 3) / 4, 256, 0, stream>>>(h, hb, eseq, rec, hi, hj, he, We,
                                           off_e, deg_e, deg_n, out, N);
}

// Round 6
// 578.084 us; speedup vs baseline: 1.2387x; 1.2387x over previous
//
#include <hip/hip_runtime.h>
#include <math.h>

#define NEG_SLOPE 0.05f

__device__ __forceinline__ float leaky(float x){ return x >= 0.f ? x : NEG_SLOPE * x; }

// bf16 helpers (RNE pack, truncated-float unpack)
__device__ __forceinline__ unsigned short f2bf(float f){
    unsigned u = __float_as_uint(f);
    unsigned r = u + 0x7FFFu + ((u >> 16) & 1u);
    return (unsigned short)(r >> 16);
}
__device__ __forceinline__ float bf2f(unsigned short us){
    return __uint_as_float((unsigned)us << 16);
}

// ---------------- GEMM h = x @ Wn^T (+ bf16 copy + fused hi/hj/he epilogue + deg/ctr zeroing) ----------------
__global__ __launch_bounds__(256) void k_gemm_h(const float* __restrict__ A, const float* __restrict__ B,
        const float* __restrict__ a_node, const float* __restrict__ a_edge,
        float* __restrict__ C, unsigned short* __restrict__ Cb,
        float* __restrict__ hi, float* __restrict__ hj, float* __restrict__ he,
        int* __restrict__ deg_n, int* __restrict__ deg_o, int* __restrict__ ctr, int M){
    const int K = 128;
    __shared__ float As[K][68];
    __shared__ float Bs[K][68];
    const int m0 = blockIdx.x * 64;
    const int t = threadIdx.x;
    // fused init: zero degree arrays + counters (consumed by later kernels)
    int gt = blockIdx.x * 256 + t;
    if (gt < M){ deg_n[gt] = 0; deg_o[gt] = 0; }
    if (gt == 0){ ctr[0] = 0; ctr[1] = 0; }
    for (int i = t; i < 16 * K; i += 256){
        int d = i & 63, kq = i >> 6;
        float4 b = *(const float4*)&B[(size_t)d * K + kq * 4];
        Bs[kq*4+0][d] = b.x; Bs[kq*4+1][d] = b.y; Bs[kq*4+2][d] = b.z; Bs[kq*4+3][d] = b.w;
    }
    for (int i = t; i < 16 * K; i += 256){
        int r = i & 63, kq = i >> 6;
        int m = m0 + r;
        float4 a = make_float4(0.f, 0.f, 0.f, 0.f);
        if (m < M) a = *(const float4*)&A[(size_t)m * K + kq * 4];
        As[kq*4+0][r] = a.x; As[kq*4+1][r] = a.y; As[kq*4+2][r] = a.z; As[kq*4+3][r] = a.w;
    }
    __syncthreads();
    const int tx = t & 15, ty = t >> 4;
    float acc[4][4] = {};
    #pragma unroll 4
    for (int k = 0; k < K; k++){
        float4 a4 = *(const float4*)&As[k][ty * 4];
        float4 b4 = *(const float4*)&Bs[k][tx * 4];
        float av[4] = {a4.x, a4.y, a4.z, a4.w};
        float bv[4] = {b4.x, b4.y, b4.z, b4.w};
        #pragma unroll
        for (int r = 0; r < 4; r++)
            #pragma unroll
            for (int c = 0; c < 4; c++)
                acc[r][c] = fmaf(av[r], bv[c], acc[r][c]);
    }
    #pragma unroll
    for (int r = 0; r < 4; r++){
        int m = m0 + ty * 4 + r;
        if (m < M){
            float4 o = make_float4(acc[r][0], acc[r][1], acc[r][2], acc[r][3]);
            *(float4*)&C[(size_t)m * 64 + tx * 4] = o;
            uint2 u;
            u.x = (unsigned)f2bf(o.x) | ((unsigned)f2bf(o.y) << 16);
            u.y = (unsigned)f2bf(o.z) | ((unsigned)f2bf(o.w) << 16);
            *(uint2*)&Cb[(size_t)m * 64 + tx * 4] = u;
        }
    }
    // fused per-row scalars: hi = h.a_node[:64], hj = h.a_node[64:], he = h.a_edge[:64]
    float4 an1 = *(const float4*)&a_node[tx * 4];
    float4 an2 = *(const float4*)&a_node[64 + tx * 4];
    float4 ae1 = *(const float4*)&a_edge[tx * 4];
    float p1[4], p2[4], p3[4];
    #pragma unroll
    for (int r = 0; r < 4; r++){
        p1[r] = acc[r][0]*an1.x + acc[r][1]*an1.y + acc[r][2]*an1.z + acc[r][3]*an1.w;
        p2[r] = acc[r][0]*an2.x + acc[r][1]*an2.y + acc[r][2]*an2.z + acc[r][3]*an2.w;
        p3[r] = acc[r][0]*ae1.x + acc[r][1]*ae1.y + acc[r][2]*ae1.z + acc[r][3]*ae1.w;
    }
    #pragma unroll
    for (int m = 1; m < 16; m <<= 1){
        #pragma unroll
        for (int r = 0; r < 4; r++){
            p1[r] += __shfl_xor(p1[r], m);
            p2[r] += __shfl_xor(p2[r], m);
            p3[r] += __shfl_xor(p3[r], m);
        }
    }
    if (tx == 0){
        #pragma unroll
        for (int r = 0; r < 4; r++){
            int m = m0 + ty * 4 + r;
            if (m < M){ hi[m] = p1[r]; hj[m] = p2[r]; he[m] = p3[r]; }
        }
    }
}

// ---------------- coalesced ea stream: ge + bf16 copy + fused degree count; vv computed in-block ----------------
__global__ __launch_bounds__(256) void k_ge2(const float* __restrict__ ea, const int* __restrict__ idx,
        const float* __restrict__ We, const float* __restrict__ a_edge,
        float* __restrict__ ge, unsigned short* __restrict__ eab,
        int* __restrict__ deg_n, int* __restrict__ deg_o, int E){
    __shared__ float vvs[64];
    int t = threadIdx.x;
    if (t < 64){
        float s = 0.f;
        for (int d = 0; d < 64; d++) s = fmaf(We[d * 64 + t], a_edge[64 + d], s);
        vvs[t] = s;
    }
    __syncthreads();
    int l = t & 63;
    int gw = (blockIdx.x * 256 + t) >> 6;   // global wave id
    int nw = (gridDim.x * 256) >> 6;
    int seg = l & 15, rl = l >> 4;
    float4 v4 = *(const float4*)&vvs[seg * 4];
    for (int r0 = gw * 4; r0 < E; r0 += nw * 4){
        int row = r0 + rl;
        if (row < E){
            float4 a = *(const float4*)&ea[(size_t)row * 64 + seg * 4];
            float s = a.x*v4.x + a.y*v4.y + a.z*v4.z + a.w*v4.w;
            uint2 u;
            u.x = (unsigned)f2bf(a.x) | ((unsigned)f2bf(a.y) << 16);
            u.y = (unsigned)f2bf(a.z) | ((unsigned)f2bf(a.w) << 16);
            *(uint2*)&eab[(size_t)row * 64 + seg * 4] = u;
            #pragma unroll
            for (int m = 1; m < 16; m <<= 1) s += __shfl_xor(s, m);
            if (seg == 0){
                ge[row] = s;
                int i0 = idx[row], i1 = idx[E + row];
                atomicAdd(&deg_n[i0], 1);
                atomicAdd(&deg_o[i1], 1);
            }
        }
    }
}

// ---------------- offset assignment: wave shfl-scan + one atomic per wave (ranges disjoint, order free) ----------------
__global__ __launch_bounds__(256) void k_off(const int* __restrict__ deg_n, const int* __restrict__ deg_o,
        int* __restrict__ deg_e,
        int* __restrict__ off_n, int* __restrict__ cur_n,
        int* __restrict__ off_e, int* __restrict__ cur_e,
        int* __restrict__ ctr, int N){
    int i = blockIdx.x * 256 + threadIdx.x;
    int lane = threadIdx.x & 63;
    int dn = 0, de = 0;
    if (i < N){
        dn = deg_n[i];
        de = dn + deg_o[i];
    }
    int pn = dn, pe = de;   // inclusive wave scan
    #pragma unroll
    for (int d = 1; d < 64; d <<= 1){
        int on = __shfl_up(pn, d), oe = __shfl_up(pe, d);
        if (lane >= d){ pn += on; pe += oe; }
    }
    int base_n = 0, base_e = 0;
    if (lane == 63){
        base_n = atomicAdd(&ctr[0], pn);
        base_e = atomicAdd(&ctr[1], pe);
    }
    base_n = __shfl(base_n, 63);
    base_e = __shfl(base_e, 63);
    if (i < N){
        int on = base_n + pn - dn;   // exclusive within wave
        int oe = base_e + pe - de;
        off_n[i] = on; cur_n[i] = on;
        off_e[i] = oe; cur_e[i] = oe;
        deg_e[i] = de;
    }
}

// ---------------- XCD-partitioned fill; records carry the attention scalar ----------------
__global__ __launch_bounds__(256) void k_fill(const int* __restrict__ idx,
        const float* __restrict__ hj, const float* __restrict__ ge,
        int* __restrict__ cur_n, int* __restrict__ cur_e,
        int2* __restrict__ adj_n, int2* __restrict__ adj_e, int E, int N){
    int g = blockIdx.x & 7;
    int lo = (int)(((long long)g * N) >> 3), hi = (int)(((long long)(g + 1) * N) >> 3);
    int nblk = gridDim.x >> 3;
    int start = ((blockIdx.x >> 3) * 256) + threadIdx.x;
    int stride = nblk * 256;
    for (int k = start; k < E; k += stride){
        int i0 = idx[k], i1 = idx[E + k];
        bool t0 = (i0 >= lo && i0 < hi), t1 = (i1 >= lo && i1 < hi);
        if (t0 | t1){
            int gb = __float_as_int(ge[k]);
            if (t0){
                adj_n[atomicAdd(&cur_n[i0], 1)] = make_int2(i1, __float_as_int(hj[i1]));
                adj_e[atomicAdd(&cur_e[i0], 1)] = make_int2(k, gb);
            }
            if (t1) adj_e[atomicAdd(&cur_e[i1], 1)] = make_int2(k, gb);
        }
    }
}

// ---------------- merged output kernel: 16 records/iter (4 gathers in flight per lane) ----------------
// blocks [0, nb_node): node branch -> out[:, :64]
// blocks [nb_node, 2*nb_node): edge branch + fused We matvec -> out[:, 64:]
__global__ __launch_bounds__(256) void k_out(const float* __restrict__ h,
        const unsigned short* __restrict__ hb, const unsigned short* __restrict__ eab,
        const float* __restrict__ hi, const float* __restrict__ hj, const float* __restrict__ he,
        const float* __restrict__ We,
        const int* __restrict__ off_n, const int* __restrict__ deg_n, const int2* __restrict__ adj_n,
        const int* __restrict__ off_e, const int* __restrict__ deg_e, const int2* __restrict__ adj_e,
        float* __restrict__ out, int N, int nb_node){
    __shared__ float WeT[64][65];
    __shared__ float valS[4][64];
    const int lane = threadIdx.x & 63;
    const int w = threadIdx.x >> 6;
    const int rl = lane >> 4, seg = lane & 15;

    if (blockIdx.x < nb_node){
        // ---------- node branch ----------
        int i = (blockIdx.x * 256 + (int)threadIdx.x) >> 6;
        if (i >= N) return;
        float hi_i = hi[i];
        int cnt = deg_n[i];
        int p = off_n[i];
        int e = p + cnt;
        float a0 = 0.f, a1 = 0.f, a2 = 0.f, a3 = 0.f, sp = 0.f;
        for (; p + 16 <= e; p += 16){
            int2 q0 = adj_n[p + rl];
            int2 q1 = adj_n[p + 4 + rl];
            int2 q2 = adj_n[p + 8 + rl];
            int2 q3 = adj_n[p + 12 + rl];
            uint2 u0 = *(const uint2*)&hb[(size_t)q0.x * 64 + seg * 4];
            uint2 u1 = *(const uint2*)&hb[(size_t)q1.x * 64 + seg * 4];
            uint2 u2 = *(const uint2*)&hb[(size_t)q2.x * 64 + seg * 4];
            uint2 u3 = *(const uint2*)&hb[(size_t)q3.x * 64 + seg * 4];
            float w0 = __expf(leaky(hi_i + __int_as_float(q0.y)));
            float w1 = __expf(leaky(hi_i + __int_as_float(q1.y)));
            float w2 = __expf(leaky(hi_i + __int_as_float(q2.y)));
            float w3 = __expf(leaky(hi_i + __int_as_float(q3.y)));
            a0 = fmaf(w0, bf2f((unsigned short)u0.x), a0);
            a1 = fmaf(w0, bf2f((unsigned short)(u0.x >> 16)), a1);
            a2 = fmaf(w0, bf2f((unsigned short)u0.y), a2);
            a3 = fmaf(w0, bf2f((unsigned short)(u0.y >> 16)), a3);
            a0 = fmaf(w1, bf2f((unsigned short)u1.x), a0);
            a1 = fmaf(w1, bf2f((unsigned short)(u1.x >> 16)), a1);
            a2 = fmaf(w1, bf2f((unsigned short)u1.y), a2);
            a3 = fmaf(w1, bf2f((unsigned short)(u1.y >> 16)), a3);
            a0 = fmaf(w2, bf2f((unsigned short)u2.x), a0);
            a1 = fmaf(w2, bf2f((unsigned short)(u2.x >> 16)), a1);
            a2 = fmaf(w2, bf2f((unsigned short)u2.y), a2);
            a3 = fmaf(w2, bf2f((unsigned short)(u2.y >> 16)), a3);
            a0 = fmaf(w3, bf2f((unsigned short)u3.x), a0);
            a1 = fmaf(w3, bf2f((unsigned short)(u3.x >> 16)), a1);
            a2 = fmaf(w3, bf2f((unsigned short)u3.y), a2);
            a3 = fmaf(w3, bf2f((unsigned short)(u3.y >> 16)), a3);
            sp += (w0 + w1) + (w2 + w3);
        }
        if (p + 8 <= e){
            int2 q0 = adj_n[p + rl];
            int2 q1 = adj_n[p + 4 + rl];
            uint2 u0 = *(const uint2*)&hb[(size_t)q0.x * 64 + seg * 4];
            uint2 u1 = *(const uint2*)&hb[(size_t)q1.x * 64 + seg * 4];
            float w0 = __expf(leaky(hi_i + __int_as_float(q0.y)));
            float w1 = __expf(leaky(hi_i + __int_as_float(q1.y)));
            a0 = fmaf(w0, bf2f((unsigned short)u0.x), a0);
            a1 = fmaf(w0, bf2f((unsigned short)(u0.x >> 16)), a1);
            a2 = fmaf(w0, bf2f((unsigned short)u0.y), a2);
            a3 = fmaf(w0, bf2f((unsigned short)(u0.y >> 16)), a3);
            a0 = fmaf(w1, bf2f((unsigned short)u1.x), a0);
            a1 = fmaf(w1, bf2f((unsigned short)(u1.x >> 16)), a1);
            a2 = fmaf(w1, bf2f((unsigned short)u1.y), a2);
            a3 = fmaf(w1, bf2f((unsigned short)(u1.y >> 16)), a3);
            sp += w0 + w1;
            p += 8;
        }
        if (p + 4 <= e){
            int2 q0 = adj_n[p + rl];
            uint2 u0 = *(const uint2*)&hb[(size_t)q0.x * 64 + seg * 4];
            float w0 = __expf(leaky(hi_i + __int_as_float(q0.y)));
            a0 = fmaf(w0, bf2f((unsigned short)u0.x), a0);
            a1 = fmaf(w0, bf2f((unsigned short)(u0.x >> 16)), a1);
            a2 = fmaf(w0, bf2f((unsigned short)u0.y), a2);
            a3 = fmaf(w0, bf2f((unsigned short)(u0.y >> 16)), a3);
            sp += w0;
            p += 4;
        }
        int rem = e - p;
        if (rl < rem){
            int2 q0 = adj_n[p + rl];
            uint2 u0 = *(const uint2*)&hb[(size_t)q0.x * 64 + seg * 4];
            float w0 = __expf(leaky(hi_i + __int_as_float(q0.y)));
            a0 = fmaf(w0, bf2f((unsigned short)u0.x), a0);
            a1 = fmaf(w0, bf2f((unsigned short)(u0.x >> 16)), a1);
            a2 = fmaf(w0, bf2f((unsigned short)u0.y), a2);
            a3 = fmaf(w0, bf2f((unsigned short)(u0.y >> 16)), a3);
            sp += w0;
        }
        a0 += __shfl_xor(a0, 16); a0 += __shfl_xor(a0, 32);
        a1 += __shfl_xor(a1, 16); a1 += __shfl_xor(a1, 32);
        a2 += __shfl_xor(a2, 16); a2 += __shfl_xor(a2, 32);
        a3 += __shfl_xor(a3, 16); a3 += __shfl_xor(a3, 32);
        sp += __shfl_xor(sp, 16); sp += __shfl_xor(sp, 32);
        if (rl == 0){
            float4 h4 = *(const float4*)&h[(size_t)i * 64 + seg * 4];
            float wself = __expf(leaky(hi_i + hj[i]));
            float s = sp + wself;
            float inv = 1.f / (s * (float)(cnt + 1));
            float4 o;
            o.x = leaky(fmaf(wself, h4.x, a0) * inv);
            o.y = leaky(fmaf(wself, h4.y, a1) * inv);
            o.z = leaky(fmaf(wself, h4.z, a2) * inv);
            o.w = leaky(fmaf(wself, h4.w, a3) * inv);
            *(float4*)&out[(size_t)i * 128 + seg * 4] = o;
        }
    } else {
        // ---------- edge branch ----------
        for (int t2 = threadIdx.x; t2 < 1024; t2 += 256){
            int d = t2 >> 4, c0 = (t2 & 15) * 4;
            float4 v = *(const float4*)&We[d * 64 + c0];
            WeT[c0+0][d] = v.x; WeT[c0+1][d] = v.y; WeT[c0+2][d] = v.z; WeT[c0+3][d] = v.w;
        }
        int i = ((blockIdx.x - nb_node) * 256 + (int)threadIdx.x) >> 6;
        const int iok = (i < N);
        float v0 = 0.f, v1 = 0.f, v2 = 0.f, v3 = 0.f;
        if (iok){
            float he_i = he[i];
            int cnt = deg_e[i];
            int p = off_e[i];
            int e = p + cnt;
            float a0 = 0.f, a1 = 0.f, a2 = 0.f, a3 = 0.f, sp = 0.f;
            for (; p + 16 <= e; p += 16){
                int2 q0 = adj_e[p + rl];
                int2 q1 = adj_e[p + 4 + rl];
                int2 q2 = adj_e[p + 8 + rl];
                int2 q3 = adj_e[p + 12 + rl];
                uint2 u0 = *(const uint2*)&eab[(size_t)q0.x * 64 + seg * 4];
                uint2 u1 = *(const uint2*)&eab[(size_t)q1.x * 64 + seg * 4];
                uint2 u2 = *(const uint2*)&eab[(size_t)q2.x * 64 + seg * 4];
                uint2 u3 = *(const uint2*)&eab[(size_t)q3.x * 64 + seg * 4];
                float w0 = __expf(leaky(he_i + __int_as_float(q0.y)));
                float w1 = __expf(leaky(he_i + __int_as_float(q1.y)));
                float w2 = __expf(leaky(he_i + __int_as_float(q2.y)));
                float w3 = __expf(leaky(he_i + __int_as_float(q3.y)));
                a0 = fmaf(w0, bf2f((unsigned short)u0.x), a0);
                a1 = fmaf(w0, bf2f((unsigned short)(u0.x >> 16)), a1);
                a2 = fmaf(w0, bf2f((unsigned short)u0.y), a2);
                a3 = fmaf(w0, bf2f((unsigned short)(u0.y >> 16)), a3);
                a0 = fmaf(w1, bf2f((unsigned short)u1.x), a0);
                a1 = fmaf(w1, bf2f((unsigned short)(u1.x >> 16)), a1);
                a2 = fmaf(w1, bf2f((unsigned short)u1.y), a2);
                a3 = fmaf(w1, bf2f((unsigned short)(u1.y >> 16)), a3);
                a0 = fmaf(w2, bf2f((unsigned short)u2.x), a0);
                a1 = fmaf(w2, bf2f((unsigned short)(u2.x >> 16)), a1);
                a2 = fmaf(w2, bf2f((unsigned short)u2.y), a2);
                a3 = fmaf(w2, bf2f((unsigned short)(u2.y >> 16)), a3);
                a0 = fmaf(w3, bf2f((unsigned short)u3.x), a0);
                a1 = fmaf(w3, bf2f((unsigned short)(u3.x >> 16)), a1);
                a2 = fmaf(w3, bf2f((unsigned short)u3.y), a2);
                a3 = fmaf(w3, bf2f((unsigned short)(u3.y >> 16)), a3);
                sp += (w0 + w1) + (w2 + w3);
            }
            if (p + 8 <= e){
                int2 q0 = adj_e[p + rl];
                int2 q1 = adj_e[p + 4 + rl];
                uint2 u0 = *(const uint2*)&eab[(size_t)q0.x * 64 + seg * 4];
                uint2 u1 = *(const uint2*)&eab[(size_t)q1.x * 64 + seg * 4];
                float w0 = __expf(leaky(he_i + __int_as_float(q0.y)));
                float w1 = __expf(leaky(he_i + __int_as_float(q1.y)));
                a0 = fmaf(w0, bf2f((unsigned short)u0.x), a0);
                a1 = fmaf(w0, bf2f((unsigned short)(u0.x >> 16)), a1);
                a2 = fmaf(w0, bf2f((unsigned short)u0.y), a2);
                a3 = fmaf(w0, bf2f((unsigned short)(u0.y >> 16)), a3);
                a0 = fmaf(w1, bf2f((unsigned short)u1.x), a0);
                a1 = fmaf(w1, bf2f((unsigned short)(u1.x >> 16)), a1);
                a2 = fmaf(w1, bf2f((unsigned short)u1.y), a2);
                a3 = fmaf(w1, bf2f((unsigned short)(u1.y >> 16)), a3);
                sp += w0 + w1;
                p += 8;
            }
            if (p + 4 <= e){
                int2 q0 = adj_e[p + rl];
                uint2 u0 = *(const uint2*)&eab[(size_t)q0.x * 64 + seg * 4];
                float w0 = __expf(leaky(he_i + __int_as_float(q0.y)));
                a0 = fmaf(w0, bf2f((unsigned short)u0.x), a0);
                a1 = fmaf(w0, bf2f((unsigned short)(u0.x >> 16)), a1);
                a2 = fmaf(w0, bf2f((unsigned short)u0.y), a2);
                a3 = fmaf(w0, bf2f((unsigned short)(u0.y >> 16)), a3);
                sp += w0;
                p += 4;
            }
            int rem = e - p;
            if (rl < rem){
                int2 q0 = adj_e[p + rl];
                uint2 u0 = *(const uint2*)&eab[(size_t)q0.x * 64 + seg * 4];
                float w0 = __expf(leaky(he_i + __int_as_float(q0.y)));
                a0 = fmaf(w0, bf2f((unsigned short)u0.x), a0);
                a1 = fmaf(w0, bf2f((unsigned short)(u0.x >> 16)), a1);
                a2 = fmaf(w0, bf2f((unsigned short)u0.y), a2);
                a3 = fmaf(w0, bf2f((unsigned short)(u0.y >> 16)), a3);
                sp += w0;
            }
            a0 += __shfl_xor(a0, 16); a0 += __shfl_xor(a0, 32);
            a1 += __shfl_xor(a1, 16); a1 += __shfl_xor(a1, 32);
            a2 += __shfl_xor(a2, 16); a2 += __shfl_xor(a2, 32);
            a3 += __shfl_xor(a3, 16); a3 += __shfl_xor(a3, 32);
            sp += __shfl_xor(sp, 16); sp += __shfl_xor(sp, 32);
            if (cnt > 0){
                float inv = 1.f / (sp * (float)cnt);
                v0 = a0 * inv; v1 = a1 * inv; v2 = a2 * inv; v3 = a3 * inv;
            }
        }
        __syncthreads();                 // WeT ready
        if (rl == 0) *(float4*)&valS[w][seg * 4] = make_float4(v0, v1, v2, v3);
        __syncthreads();                 // valS visible
        if (iok){
            float acc2 = 0.f;
            #pragma unroll
            for (int c4 = 0; c4 < 16; c4++){
                float4 vb = *(const float4*)&valS[w][c4 * 4];
                acc2 = fmaf(vb.x, WeT[c4*4+0][lane], acc2);
                acc2 = fmaf(vb.y, WeT[c4*4+1][lane], acc2);
                acc2 = fmaf(vb.z, WeT[c4*4+2][lane], acc2);
                acc2 = fmaf(vb.w, WeT[c4*4+3][lane], acc2);
            }
            out[(size_t)i * 128 + 64 + lane] = leaky(acc2);
        }
    }
}

extern "C" void kernel_launch(void* const* d_in, const int* in_sizes, int n_in,
                              void* d_out, int out_size, void* d_ws, size_t ws_size,
                              hipStream_t stream){
    const float* x      = (const float*)d_in[0];
    const float* ea     = (const float*)d_in[1];
    const int*   idx    = (const int*)  d_in[2];
    const float* Wn     = (const float*)d_in[3];
    const float* We     = (const float*)d_in[4];
    const float* a_node = (const float*)d_in[5];
    const float* a_edge = (const float*)d_in[6];
    float* out = (float*)d_out;

    const int N = in_sizes[0] / 128;   // 50000
    const int E = in_sizes[1] / 64;    // 800000

    float* p = (float*)d_ws;
    float* h      = p; p += (size_t)N * 64;
    float* hi     = p; p += N;
    float* hj     = p; p += N;
    float* he     = p; p += N;
    float* ge     = p; p += E;
    unsigned short* hb  = (unsigned short*)p; p += (size_t)N * 32;   // bf16 h
    unsigned short* eab = (unsigned short*)p; p += (size_t)E * 32;   // bf16 ea
    int* deg_n = (int*)p; p += N;
    int* deg_o = (int*)p; p += N;
    int* deg_e = (int*)p; p += N;
    int* off_n = (int*)p; p += N;
    int* off_e = (int*)p; p += N;
    int* cur_n = (int*)p; p += N;
    int* cur_e = (int*)p; p += N;
    int* ctr   = (int*)p; p += 4;
    int2* adj_n = (int2*)p; p += (size_t)2 * E;
    int2* adj_e = (int2*)p; p += (size_t)4 * E;

    const int nb = (N + 3) / 4;

    k_gemm_h<<<(N + 63) / 64, 256, 0, stream>>>(x, Wn, a_node, a_edge, h, hb, hi, hj, he,
                                                deg_n, deg_o, ctr, N);
    k_ge2<<<2048, 256, 0, stream>>>(ea, idx, We, a_edge, ge, eab, deg_n, deg_o, E);
    k_off<<<(N + 255) / 256, 256, 0, stream>>>(deg_n, deg_o, deg_e, off_n, cur_n, off_e, cur_e, ctr, N);
    k_fill<<<1024, 256, 0, stream>>>(idx, hj, ge, cur_n, cur_e, adj_n, adj_e, E, N);
    k_out<<<2 * nb, 256, 0, stream>>>(h, hb, eab, hi, hj, he, We,
                                      off_n, deg_n, adj_n, off_e, deg_e, adj_e, out, N, nb);
}